// Round 4
// baseline (364.602 us; speedup 1.0000x reference)
//
#include <hip/hip_runtime.h>
#include <stdint.h>

#define TLEN   2048
#define DMODEL 1024
#define DINNER 2048
#define MROWS  8192   // B*T
#define CHUNK  128
#define FRPAD  2064   // u16 row stride of sxc (16B-aligned, 4-way-bank for MFMA frags)

typedef unsigned short u16;
typedef __bf16 bf16x8 __attribute__((ext_vector_type(8)));
typedef float  f32x4  __attribute__((ext_vector_type(4)));

__device__ __forceinline__ float bf2f(u16 u) {
  union { unsigned int i; float f; } v; v.i = ((unsigned int)u) << 16; return v.f;
}
__device__ __forceinline__ u16 f2bf(float f) {
  union { float f; unsigned int u; } v; v.f = f;
  unsigned int u = v.u;
  return (u16)((u + 0x7fffu + ((u >> 16) & 1u)) >> 16);
}
__device__ __forceinline__ float silu_f(float x) { return x / (1.f + __expf(-x)); }

__device__ __forceinline__ void async16(const u16* g, u16* l) {
  __builtin_amdgcn_global_load_lds(
      (const __attribute__((address_space(1))) void*)(g),
      (__attribute__((address_space(3))) void*)(l),
      16, 0, 0);
}

__device__ __forceinline__ void unpack8(uint4 raw, float* v) {
  v[0] = bf2f(raw.x & 0xffff); v[1] = bf2f(raw.x >> 16);
  v[2] = bf2f(raw.y & 0xffff); v[3] = bf2f(raw.y >> 16);
  v[4] = bf2f(raw.z & 0xffff); v[5] = bf2f(raw.z >> 16);
  v[6] = bf2f(raw.w & 0xffff); v[7] = bf2f(raw.w >> 16);
}
__device__ __forceinline__ uint4 pack8(const u16* o) {
  uint4 r;
  r.x = (unsigned)o[0] | ((unsigned)o[1] << 16);
  r.y = (unsigned)o[2] | ((unsigned)o[3] << 16);
  r.z = (unsigned)o[4] | ((unsigned)o[5] << 16);
  r.w = (unsigned)o[6] | ((unsigned)o[7] << 16);
  return r;
}

// ---------------- fp32 -> bf16 conversion: x, in_proj_w, out_proj_w, xpw -------
__global__ __launch_bounds__(256) void k_convert(const float* __restrict__ x,
    const float* __restrict__ w1, const float* __restrict__ w3,
    const float* __restrict__ xpw,
    u16* __restrict__ xb, u16* __restrict__ w1b, u16* __restrict__ w3b,
    u16* __restrict__ xpwb) {
  int i = blockIdx.x * 256 + threadIdx.x;           // one float4 per thread
  const int nx  = MROWS * DMODEL / 4;               // 2097152
  const int nw1 = 2 * DINNER * DMODEL / 4;          // 1048576
  const int nw3 = DMODEL * DINNER / 4;              //  524288
  const float* src; u16* dst; int j;
  if (i < nx)                  { src = x;   dst = xb;   j = i; }
  else if (i < nx + nw1)       { src = w1;  dst = w1b;  j = i - nx; }
  else if (i < nx + nw1 + nw3) { src = w3;  dst = w3b;  j = i - nx - nw1; }
  else                         { src = xpw; dst = xpwb; j = i - nx - nw1 - nw3; }
  float4 v = ((const float4*)src)[j];
  ushort4 o;
  o.x = f2bf(v.x); o.y = f2bf(v.y); o.z = f2bf(v.z); o.w = f2bf(v.w);
  ((ushort4*)dst)[j] = o;
}

// ---------------- bf16 MFMA GEMM: C[M,N] = A[M,K] * B[N,K]^T (m97 structure) ---
template<int N, int K, bool OUT_BF16>
__global__ __launch_bounds__(256) void k_gemm_bt(const u16* __restrict__ A,
    const u16* __restrict__ B, void* __restrict__ C) {
  __shared__ u16 sA[128 * 32];
  __shared__ u16 sB[128 * 32];
  const int tid  = threadIdx.x;
  const int lane = tid & 63;
  const int wave = tid >> 6;            // 0..3
  const int wm   = (wave >> 1) * 64;
  const int wn   = (wave & 1) * 64;
  const int fr   = lane & 15;
  const int q    = lane >> 4;
  const size_t blockM = (size_t)blockIdx.y * 128;
  const size_t blockN = (size_t)blockIdx.x * 128;

  const int srow = lane >> 2;
  const int scol = (lane & 3) * 8;
  const u16* gA = A + (blockM + (size_t)wave * 32 + srow) * (size_t)K + scol;
  const u16* gB = B + (blockN + (size_t)wave * 32 + srow) * (size_t)K + scol;
  u16* lA = sA + wave * 1024;
  u16* lB = sB + wave * 1024;

  f32x4 acc[4][4] = {};

  for (int kt = 0; kt < K; kt += 32) {
    async16(gA + kt,                   lA);
    async16(gA + 16 * (size_t)K + kt,  lA + 512);
    async16(gB + kt,                   lB);
    async16(gB + 16 * (size_t)K + kt,  lB + 512);
    __syncthreads();

    bf16x8 af[4], bfr[4];
    #pragma unroll
    for (int tm = 0; tm < 4; tm++)
      af[tm] = *(const bf16x8*)(sA + (wm + tm * 16 + fr) * 32 + q * 8);
    #pragma unroll
    for (int tn = 0; tn < 4; tn++)
      bfr[tn] = *(const bf16x8*)(sB + (wn + tn * 16 + fr) * 32 + q * 8);
    #pragma unroll
    for (int tm = 0; tm < 4; tm++)
      #pragma unroll
      for (int tn = 0; tn < 4; tn++)
        acc[tm][tn] = __builtin_amdgcn_mfma_f32_16x16x32_bf16(
            af[tm], bfr[tn], acc[tm][tn], 0, 0, 0);
    __syncthreads();
  }

  #pragma unroll
  for (int tm = 0; tm < 4; tm++)
    #pragma unroll
    for (int tn = 0; tn < 4; tn++)
      #pragma unroll
      for (int r = 0; r < 4; r++) {
        size_t row = blockM + wm + tm * 16 + q * 4 + r;
        size_t col = blockN + wn + tn * 16 + fr;
        float v = acc[tm][tn][r];
        if (OUT_BF16) ((u16*)C)[row * N + col] = f2bf(v);
        else          ((float*)C)[row * N + col] = v;
      }
}

// ---------------- k_front: conv+silu -> bssm (MFMA) -> alpha -> 16-row carry ---
// 512 blocks = (b, c16); block handles 16 rows x 2048 d. Thread owns 8 d's.
__global__ __launch_bounds__(256) void k_front(
    const u16* __restrict__ xz, const float* __restrict__ cw,
    const float* __restrict__ cb, const u16* __restrict__ xpwb,
    const float* __restrict__ dtw, const float* __restrict__ dtb,
    u16* __restrict__ xc, float* __restrict__ alpha,
    float* __restrict__ P16, float* __restrict__ carry16) {
  __shared__ u16   sxc[16 * FRPAD];     // 66048 B
  __shared__ float red[4][16][16];      // 4 KB
  __shared__ float sB[16][16];          // 1 KB
  __shared__ float redA[4][16];
  __shared__ float salpha[16];

  const int tid = threadIdx.x;
  const int c16 = blockIdx.x & 127;
  const int b   = blockIdx.x >> 7;
  const int t0  = c16 * 16;
  const size_t row0 = (size_t)b * TLEN + t0;
  const int d0  = tid * 8;

  // ---- phase 1: depthwise causal conv + silu (rolling window) ----
  float w0[8], w1[8], w2[8], w3[8], bias[8];
  #pragma unroll
  for (int j = 0; j < 8; j++) {
    float4 w = ((const float4*)cw)[d0 + j];
    w0[j] = w.x; w1[j] = w.y; w2[j] = w.z; w3[j] = w.w;
    bias[j] = cb[d0 + j];
  }
  float p3[8], p2[8], p1[8], cur[8];
  #pragma unroll
  for (int j = 0; j < 8; j++) { p3[j] = 0.f; p2[j] = 0.f; p1[j] = 0.f; }
  if (t0 >= 3) {
    uint4 r3 = *(const uint4*)(xz + ((size_t)(b * TLEN + t0 - 3)) * 4096 + d0);
    uint4 r2 = *(const uint4*)(xz + ((size_t)(b * TLEN + t0 - 2)) * 4096 + d0);
    uint4 r1 = *(const uint4*)(xz + ((size_t)(b * TLEN + t0 - 1)) * 4096 + d0);
    unpack8(r3, p3); unpack8(r2, p2); unpack8(r1, p1);
  }
  #pragma unroll 4
  for (int r = 0; r < 16; r++) {
    uint4 rc = *(const uint4*)(xz + (row0 + r) * 4096 + d0);
    unpack8(rc, cur);
    u16 o[8];
    #pragma unroll
    for (int j = 0; j < 8; j++) {
      float a = bias[j] + w0[j] * p3[j] + w1[j] * p2[j] + w2[j] * p1[j] + w3[j] * cur[j];
      o[j] = f2bf(silu_f(a));
    }
    uint4 pk = pack8(o);
    *(uint4*)(xc + (row0 + r) * DINNER + d0) = pk;
    *(uint4*)(&sxc[r * FRPAD + d0]) = pk;
    #pragma unroll
    for (int j = 0; j < 8; j++) { p3[j] = p2[j]; p2[j] = p1[j]; p1[j] = cur[j]; }
  }
  __syncthreads();

  // ---- phase 2: bssm[16x16] = sxc[16x2048] . xpwb[16x2048]^T via MFMA --------
  const int lane = tid & 63;
  const int wave = tid >> 6;            // splits K into 4x512
  const int fr   = lane & 15;
  const int q    = lane >> 4;
  {
    f32x4 acc = {};
    const int k0 = wave * 512;
    #pragma unroll
    for (int kk = 0; kk < 512; kk += 32) {
      const int kb = k0 + kk + q * 8;
      bf16x8 af = *(const bf16x8*)(&sxc[fr * FRPAD + kb]);
      bf16x8 bf_ = *(const bf16x8*)(xpwb + (size_t)fr * DINNER + kb);
      acc = __builtin_amdgcn_mfma_f32_16x16x32_bf16(af, bf_, acc, 0, 0, 0);
    }
    #pragma unroll
    for (int r = 0; r < 4; r++) red[wave][q * 4 + r][fr] = acc[r];
  }
  __syncthreads();
  { int r = tid >> 4, n = tid & 15;
    sB[r][n] = red[0][r][n] + red[1][r][n] + red[2][r][n] + red[3][r][n]; }
  __syncthreads();

  // ---- phase 3: dt = softplus(bssm . dtw^T + b); alpha = sigmoid(mean) -------
  float rowsum[16];
  #pragma unroll
  for (int r = 0; r < 16; r++) rowsum[r] = 0.f;
  #pragma unroll 1
  for (int m = 0; m < 4; m++) {
    const int dd = m * 512 + tid * 2;
    float4 w[2][4]; float bs[2];
    #pragma unroll
    for (int j = 0; j < 2; j++) {
      const float4* wp = (const float4*)(dtw + (size_t)(dd + j) * 16);
      w[j][0] = wp[0]; w[j][1] = wp[1]; w[j][2] = wp[2]; w[j][3] = wp[3];
      bs[j] = dtb[dd + j];
    }
    #pragma unroll
    for (int r = 0; r < 16; r++) {
      const float4* bp = (const float4*)sB[r];
      float4 b0 = bp[0], b1 = bp[1], b2 = bp[2], b3 = bp[3];
      float s = 0.f;
      #pragma unroll
      for (int j = 0; j < 2; j++) {
        float dot = bs[j]
          + b0.x * w[j][0].x + b0.y * w[j][0].y + b0.z * w[j][0].z + b0.w * w[j][0].w
          + b1.x * w[j][1].x + b1.y * w[j][1].y + b1.z * w[j][1].z + b1.w * w[j][1].w
          + b2.x * w[j][2].x + b2.y * w[j][2].y + b2.z * w[j][2].z + b2.w * w[j][2].w
          + b3.x * w[j][3].x + b3.y * w[j][3].y + b3.z * w[j][3].z + b3.w * w[j][3].w;
        s += (dot > 15.f) ? dot : __logf(1.f + __expf(dot));
      }
      rowsum[r] += s;
    }
  }
  #pragma unroll
  for (int r = 0; r < 16; r++)
    #pragma unroll
    for (int off = 32; off > 0; off >>= 1) rowsum[r] += __shfl_xor(rowsum[r], off);
  if ((tid & 63) == 0) {
    #pragma unroll
    for (int r = 0; r < 16; r++) redA[tid >> 6][r] = rowsum[r];
  }
  __syncthreads();
  if (tid < 16) {
    float mean = (redA[0][tid] + redA[1][tid] + redA[2][tid] + redA[3][tid]) * (1.f / DINNER);
    float a = 1.f / (1.f + __expf(-mean));
    alpha[row0 + tid] = a;
    salpha[tid] = a;
  }
  __syncthreads();

  // ---- phase 4: chunk alpha-product + local 16-row scan carry ----------------
  if (tid == 0) {
    float p = salpha[0];
    #pragma unroll
    for (int r = 1; r < 16; r++) p *= salpha[r];
    P16[b * 128 + c16] = p;
  }
  float h[8];
  #pragma unroll
  for (int j = 0; j < 8; j++) h[j] = 0.f;
  #pragma unroll 4
  for (int r = 0; r < 16; r++) {
    float a = salpha[r];
    float xv[8];
    unpack8(*(const uint4*)(&sxc[r * FRPAD + d0]), xv);
    #pragma unroll
    for (int j = 0; j < 8; j++) h[j] = a * h[j] + (1.f - a) * xv[j];
  }
  float4* cp = (float4*)(carry16 + ((size_t)(b * 128 + c16)) * DINNER + d0);
  float4 h0 = { h[0], h[1], h[2], h[3] };
  float4 h1 = { h[4], h[5], h[6], h[7] };
  cp[0] = h0; cp[1] = h1;
}

// ---------------- k_scan: carry-chain prefix + re-scan + fused gate ------------
__global__ __launch_bounds__(256) void k_scan(const u16* __restrict__ xc,
    const u16* __restrict__ xz, const float* __restrict__ alpha,
    const float* __restrict__ P16, const float* __restrict__ carry16,
    const float* __restrict__ Dp, u16* __restrict__ yg) {
  const int blk = blockIdx.x;
  const int g = blk & 7;
  const int c = (blk >> 3) & 15;
  const int b = blk >> 7;
  const int d = g * 256 + threadIdx.x;
  __shared__ float sa[CHUNK];
  if (threadIdx.x < CHUNK) sa[threadIdx.x] = alpha[b * TLEN + c * CHUNK + threadIdx.x];
  __syncthreads();

  // phase A: chunk-entry state via 16-row carry chain (c*8 links)
  float h = 0.f;
  const int ccend = c * 8;
  for (int cc = 0; cc < ccend; cc++) {
    float p  = P16[b * 128 + cc];
    float cv = carry16[((size_t)(b * 128 + cc)) * DINNER + d];
    h = p * h + cv;
  }

  // phase B: scan 128 timesteps, fused y = (h*D + xc) * silu(z)
  const float Dv = Dp[d];
  const size_t row0 = (size_t)(b * TLEN + c * CHUNK);
  #pragma unroll 4
  for (int i = 0; i < CHUNK; i++) {
    size_t row = row0 + i;
    float a = sa[i];
    float xv = bf2f(xc[row * DINNER + d]);
    h = a * h + (1.f - a) * xv;
    float zv = bf2f(xz[row * 4096 + DINNER + d]);   // z = cols [2048,4096)
    float y = h * Dv + xv;
    yg[row * DINNER + d] = f2bf(y * silu_f(zv));
  }
}

// ---------------- launch --------------------------------------------------------
extern "C" void kernel_launch(void* const* d_in, const int* in_sizes, int n_in,
                              void* d_out, int out_size, void* d_ws, size_t ws_size,
                              hipStream_t stream) {
  const float* x   = (const float*)d_in[0];
  const float* w1  = (const float*)d_in[1];
  const float* cw  = (const float*)d_in[2];
  const float* cb  = (const float*)d_in[3];
  const float* xpw = (const float*)d_in[4];
  const float* dtw = (const float*)d_in[5];
  const float* dtb = (const float*)d_in[6];
  const float* Dp  = (const float*)d_in[7];
  const float* w3  = (const float*)d_in[8];
  float* out = (float*)d_out;
  char* ws = (char*)d_ws;

  u16*   xb      = (u16*)(ws + 0);            // 16.78 MB (dead after gemm1)
  u16*   w1b     = (u16*)(ws + 16777216);     //  8.39 MB
  u16*   w3b     = (u16*)(ws + 25165824);     //  4.19 MB
  u16*   xz      = (u16*)(ws + 29360128);     // 67.11 MB  [8192][4096] bf16
  u16*   xc      = (u16*)(ws + 96468992);     // 33.55 MB  [8192][2048] bf16
  u16*   yg      = (u16*)(ws + 130023424);    // 33.55 MB  [8192][2048] bf16
  u16*   xpwb    = (u16*)(ws + 163577856);    // 64 KB     [16][2048] bf16
  float* alpha   = (float*)(ws + 163643392);  // 32 KB     [8192]
  float* P16     = (float*)(ws + 163676160);  // 2 KB      [4][128]
  float* carry16 = (float*)(ws + 0);          // 4.19 MB   [4][128][2048] (overlays dead xb)

  k_convert<<<14368, 256, 0, stream>>>(x, w1, w3, xpw, xb, w1b, w3b, xpwb);
  k_gemm_bt<4096, 1024, true ><<<dim3(32, 64), 256, 0, stream>>>(xb, w1b, xz);
  k_front  <<<512, 256, 0, stream>>>(xz, cw, cb, xpwb, dtw, dtb, xc, alpha, P16, carry16);
  k_scan   <<<512, 256, 0, stream>>>(xc, xz, alpha, P16, carry16, Dp, yg);
  k_gemm_bt<1024, 2048, false><<<dim3(8, 64), 256, 0, stream>>>(yg, w3b, out);
}

// Round 5
// 326.155 us; speedup vs baseline: 1.1179x; 1.1179x over previous
//
#include <hip/hip_runtime.h>
#include <stdint.h>

#define TLEN   2048
#define DMODEL 1024
#define DINNER 2048
#define MROWS  8192   // B*T
#define NCH    16
#define CHUNK  128

typedef unsigned short u16;
typedef __bf16 bf16x8 __attribute__((ext_vector_type(8)));
typedef float  f32x4  __attribute__((ext_vector_type(4)));

__device__ __forceinline__ float bf2f(u16 u) {
  union { unsigned int i; float f; } v; v.i = ((unsigned int)u) << 16; return v.f;
}
__device__ __forceinline__ u16 f2bf(float f) {
  union { float f; unsigned int u; } v; v.f = f;
  unsigned int u = v.u;
  return (u16)((u + 0x7fffu + ((u >> 16) & 1u)) >> 16);
}
__device__ __forceinline__ float silu_f(float x) { return x / (1.f + __expf(-x)); }

__device__ __forceinline__ void async16(const u16* g, u16* l) {
  __builtin_amdgcn_global_load_lds(
      (const __attribute__((address_space(1))) void*)(g),
      (__attribute__((address_space(3))) void*)(l),
      16, 0, 0);
}

// ---------------- fp32 -> bf16 conversion: x, in_proj_w, out_proj_w, xpw -------
__global__ __launch_bounds__(256) void k_convert(const float* __restrict__ x,
    const float* __restrict__ w1, const float* __restrict__ w3,
    const float* __restrict__ xpw,
    u16* __restrict__ xb, u16* __restrict__ w1b, u16* __restrict__ w3b,
    u16* __restrict__ xpwb) {
  int i = blockIdx.x * 256 + threadIdx.x;           // one float4 per thread
  const int nx  = MROWS * DMODEL / 4;               // 2097152
  const int nw1 = 2 * DINNER * DMODEL / 4;          // 1048576
  const int nw3 = DMODEL * DINNER / 4;              //  524288
  const float* src; u16* dst; int j;
  if (i < nx)                  { src = x;   dst = xb;   j = i; }
  else if (i < nx + nw1)       { src = w1;  dst = w1b;  j = i - nx; }
  else if (i < nx + nw1 + nw3) { src = w3;  dst = w3b;  j = i - nx - nw1; }
  else                         { src = xpw; dst = xpwb; j = i - nx - nw1 - nw3; }
  float4 v = ((const float4*)src)[j];
  ushort4 o;
  o.x = f2bf(v.x); o.y = f2bf(v.y); o.z = f2bf(v.z); o.w = f2bf(v.w);
  ((ushort4*)dst)[j] = o;
}

// ---------------- bf16 MFMA GEMM, BK=64 as two BK=32 sub-buffers ---------------
// C[M,N] = A[M,K] * B[N,K]^T. Identical staging/frag/bank pattern to the
// verified BK=32 kernel; only the barrier count per K is halved.
template<int N, int K, bool OUT_BF16>
__global__ __launch_bounds__(256) void k_gemm_bt(const u16* __restrict__ A,
    const u16* __restrict__ B, void* __restrict__ C) {
  __shared__ u16 sA[2][128 * 32];       // 16 KB
  __shared__ u16 sB[2][128 * 32];       // 16 KB
  const int tid  = threadIdx.x;
  const int lane = tid & 63;
  const int wave = tid >> 6;            // 0..3
  const int wm   = (wave >> 1) * 64;
  const int wn   = (wave & 1) * 64;
  const int fr   = lane & 15;
  const int q    = lane >> 4;
  const size_t blockM = (size_t)blockIdx.y * 128;
  const size_t blockN = (size_t)blockIdx.x * 128;

  const int srow = lane >> 2;
  const int scol = (lane & 3) * 8;
  const u16* gA = A + (blockM + (size_t)wave * 32 + srow) * (size_t)K + scol;
  const u16* gB = B + (blockN + (size_t)wave * 32 + srow) * (size_t)K + scol;
  u16* lA0 = sA[0] + wave * 1024;
  u16* lA1 = sA[1] + wave * 1024;
  u16* lB0 = sB[0] + wave * 1024;
  u16* lB1 = sB[1] + wave * 1024;

  f32x4 acc[4][4] = {};

  for (int kt = 0; kt < K; kt += 64) {
    async16(gA + kt,                        lA0);
    async16(gA + 16 * (size_t)K + kt,       lA0 + 512);
    async16(gA + kt + 32,                   lA1);
    async16(gA + 16 * (size_t)K + kt + 32,  lA1 + 512);
    async16(gB + kt,                        lB0);
    async16(gB + 16 * (size_t)K + kt,       lB0 + 512);
    async16(gB + kt + 32,                   lB1);
    async16(gB + 16 * (size_t)K + kt + 32,  lB1 + 512);
    __syncthreads();

    #pragma unroll
    for (int h = 0; h < 2; h++) {
      bf16x8 af[4], bfr[4];
      #pragma unroll
      for (int tm = 0; tm < 4; tm++)
        af[tm] = *(const bf16x8*)(sA[h] + (wm + tm * 16 + fr) * 32 + q * 8);
      #pragma unroll
      for (int tn = 0; tn < 4; tn++)
        bfr[tn] = *(const bf16x8*)(sB[h] + (wn + tn * 16 + fr) * 32 + q * 8);
      #pragma unroll
      for (int tm = 0; tm < 4; tm++)
        #pragma unroll
        for (int tn = 0; tn < 4; tn++)
          acc[tm][tn] = __builtin_amdgcn_mfma_f32_16x16x32_bf16(
              af[tm], bfr[tn], acc[tm][tn], 0, 0, 0);
    }
    __syncthreads();
  }

  #pragma unroll
  for (int tm = 0; tm < 4; tm++)
    #pragma unroll
    for (int tn = 0; tn < 4; tn++)
      #pragma unroll
      for (int r = 0; r < 4; r++) {
        size_t row = blockM + wm + tm * 16 + q * 4 + r;
        size_t col = blockN + wn + tn * 16 + fr;
        float v = acc[tm][tn][r];
        if (OUT_BF16) ((u16*)C)[row * N + col] = f2bf(v);
        else          ((float*)C)[row * N + col] = v;
      }
}

// ---------------- depthwise causal conv + SiLU: 8 timesteps per thread ---------
__global__ __launch_bounds__(256) void k_conv(const u16* __restrict__ xz,
    const float* __restrict__ cw, const float* __restrict__ cb,
    u16* __restrict__ xc) {
  int idx = blockIdx.x * 256 + threadIdx.x;   // (b, tb, d): 4*256*2048 threads
  int d  = idx & (DINNER - 1);
  int tb = (idx >> 11) & 255;                 // t-block of 8
  int b  = idx >> 19;
  float4 w = ((const float4*)cw)[d];
  float bias = cb[d];
  const u16* inp = xz + ((size_t)(b * TLEN + tb * 8)) * 4096 + d;
  float v[11];
  #pragma unroll
  for (int j = 0; j < 11; j++) {
    int t = tb * 8 - 3 + j;
    v[j] = (t >= 0) ? bf2f(inp[(ptrdiff_t)(j - 3) * 4096]) : 0.f;
  }
  u16* outp = xc + ((size_t)(b * TLEN + tb * 8)) * DINNER + d;
  #pragma unroll
  for (int i = 0; i < 8; i++) {
    float acc = bias + w.x * v[i] + w.y * v[i + 1] + w.z * v[i + 2] + w.w * v[i + 3];
    outp[(size_t)i * DINNER] = f2bf(silu_f(acc));
  }
}

// ---------------- B_ssm = xc[8192x2048] . xpwb[16x2048]^T  (skinny MFMA) -------
__global__ __launch_bounds__(256) void k_bssm(const u16* __restrict__ xc,
    const u16* __restrict__ xpwb, float* __restrict__ bssm) {
  const int tid  = threadIdx.x;
  const int lane = tid & 63;
  const int wave = tid >> 6;            // splits K
  const int fr   = lane & 15;
  const int q    = lane >> 4;
  const size_t row0 = (size_t)blockIdx.x * 32;
  const int k0 = wave * 512;

  f32x4 acc[2] = {};
  #pragma unroll
  for (int kk = 0; kk < 512; kk += 32) {
    const int kb = k0 + kk + q * 8;
    bf16x8 bfrag = *(const bf16x8*)(xpwb + (size_t)fr * DINNER + kb);
    #pragma unroll
    for (int tm = 0; tm < 2; tm++) {
      bf16x8 afrag = *(const bf16x8*)(xc + (row0 + tm * 16 + fr) * (size_t)DINNER + kb);
      acc[tm] = __builtin_amdgcn_mfma_f32_16x16x32_bf16(afrag, bfrag, acc[tm], 0, 0, 0);
    }
  }

  __shared__ float red[4][32][16];      // 8 KB
  #pragma unroll
  for (int tm = 0; tm < 2; tm++)
    #pragma unroll
    for (int r = 0; r < 4; r++)
      red[wave][tm * 16 + q * 4 + r][fr] = acc[tm][r];
  __syncthreads();
  #pragma unroll
  for (int i = tid; i < 512; i += 256) {
    int r = i >> 4, n = i & 15;
    bssm[(row0 + r) * 16 + n] =
        red[0][r][n] + red[1][r][n] + red[2][r][n] + red[3][r][n];
  }
}

// ---------------- alpha: 16 rows/block, 2 d-cols/thread/pass, 4 passes ---------
__global__ __launch_bounds__(256) void k_alpha(const float* __restrict__ bssm,
    const float* __restrict__ dtw, const float* __restrict__ dtb,
    float* __restrict__ alpha) {
  const int tid = threadIdx.x;
  const size_t row0 = (size_t)blockIdx.x * 16;
  __shared__ float4 sB[16][4];
  { int r = tid >> 4, n = tid & 15;
    ((float*)&sB[r][0])[n] = bssm[(row0 + r) * 16 + n]; }
  __syncthreads();

  float rowsum[16];
  #pragma unroll
  for (int r = 0; r < 16; r++) rowsum[r] = 0.f;

  #pragma unroll 1
  for (int m = 0; m < 4; m++) {
    const int d0 = m * 512 + tid * 2;
    float4 w[2][4]; float bias[2];
    #pragma unroll
    for (int j = 0; j < 2; j++) {
      const float4* wp = (const float4*)(dtw + (size_t)(d0 + j) * 16);
      w[j][0] = wp[0]; w[j][1] = wp[1]; w[j][2] = wp[2]; w[j][3] = wp[3];
      bias[j] = dtb[d0 + j];
    }
    #pragma unroll
    for (int r = 0; r < 16; r++) {
      float4 b0 = sB[r][0], b1 = sB[r][1], b2 = sB[r][2], b3 = sB[r][3];
      float s = 0.f;
      #pragma unroll
      for (int j = 0; j < 2; j++) {
        float dot = bias[j]
          + b0.x * w[j][0].x + b0.y * w[j][0].y + b0.z * w[j][0].z + b0.w * w[j][0].w
          + b1.x * w[j][1].x + b1.y * w[j][1].y + b1.z * w[j][1].z + b1.w * w[j][1].w
          + b2.x * w[j][2].x + b2.y * w[j][2].y + b2.z * w[j][2].z + b2.w * w[j][2].w
          + b3.x * w[j][3].x + b3.y * w[j][3].y + b3.z * w[j][3].z + b3.w * w[j][3].w;
        s += (dot > 15.f) ? dot : __logf(1.f + __expf(dot));
      }
      rowsum[r] += s;
    }
  }
  #pragma unroll
  for (int r = 0; r < 16; r++)
    #pragma unroll
    for (int off = 32; off > 0; off >>= 1) rowsum[r] += __shfl_xor(rowsum[r], off);
  __shared__ float red[4][16];
  if ((tid & 63) == 0) {
    #pragma unroll
    for (int r = 0; r < 16; r++) red[tid >> 6][r] = rowsum[r];
  }
  __syncthreads();
  if (tid < 16) {
    float mean = (red[0][tid] + red[1][tid] + red[2][tid] + red[3][tid]) * (1.f / DINNER);
    alpha[row0 + tid] = 1.f / (1.f + __expf(-mean));
  }
}

// ---------------- scan pass 1: per-chunk scan from h=0 -> carry ----------------
__global__ __launch_bounds__(256) void k_scan1(const u16* __restrict__ xc,
    const float* __restrict__ alpha, float* __restrict__ carry) {
  const int blk = blockIdx.x;           // (b, c, g)
  const int g = blk & 7;
  const int c = (blk >> 3) & 15;
  const int b = blk >> 7;
  const int d = g * 256 + threadIdx.x;
  __shared__ float sa[CHUNK];
  if (threadIdx.x < CHUNK) sa[threadIdx.x] = alpha[b * TLEN + c * CHUNK + threadIdx.x];
  __syncthreads();
  const u16* xp = xc + ((size_t)(b * TLEN + c * CHUNK)) * DINNER + d;
  float h = 0.f;
  #pragma unroll 8
  for (int i = 0; i < CHUNK; i++) {
    float a = sa[i];
    float xv = bf2f(xp[(size_t)i * DINNER]);
    h = a * h + (1.f - a) * xv;
  }
  carry[((size_t)(b * NCH + c)) * DINNER + d] = h;
}

// ---------------- scan pass 2: chunkprod + serial carry combine (in place) -----
__global__ __launch_bounds__(256) void k_scan2(float* __restrict__ carry,
    const float* __restrict__ alpha) {
  int i = blockIdx.x * 256 + threadIdx.x;   // 0..8191 = (b, d); b uniform per block
  int b = i >> 11;
  int d = i & (DINNER - 1);
  __shared__ float sP[NCH];
  if (threadIdx.x < NCH) {
    const float* ap = alpha + b * TLEN + threadIdx.x * CHUNK;
    float p = 1.f;
    for (int j = 0; j < CHUNK; j++) p *= ap[j];
    sP[threadIdx.x] = p;
  }
  __syncthreads();
  float h = 0.f;
  #pragma unroll
  for (int c = 0; c < NCH; c++) {
    size_t idx = ((size_t)(b * NCH + c)) * DINNER + d;
    float cv = carry[idx];
    carry[idx] = h;                     // now holds chunk-entry state Hs
    h = sP[c] * h + cv;
  }
}

// ---------------- scan pass 3: re-scan + fused y = (h*D + xc)*silu(z) ----------
__global__ __launch_bounds__(256) void k_scan3(const u16* __restrict__ xc,
    const u16* __restrict__ xz, const float* __restrict__ alpha,
    const float* __restrict__ Hs, const float* __restrict__ Dp,
    u16* __restrict__ yg) {
  const int blk = blockIdx.x;
  const int g = blk & 7;
  const int c = (blk >> 3) & 15;
  const int b = blk >> 7;
  const int d = g * 256 + threadIdx.x;
  __shared__ float sa[CHUNK];
  if (threadIdx.x < CHUNK) sa[threadIdx.x] = alpha[b * TLEN + c * CHUNK + threadIdx.x];
  __syncthreads();
  float h = Hs[((size_t)(b * NCH + c)) * DINNER + d];
  const float Dv = Dp[d];
  const size_t row0 = (size_t)(b * TLEN + c * CHUNK);
  #pragma unroll 4
  for (int i = 0; i < CHUNK; i++) {
    size_t row = row0 + i;
    float a = sa[i];
    float xv = bf2f(xc[row * DINNER + d]);
    h = a * h + (1.f - a) * xv;
    float zv = bf2f(xz[row * 4096 + DINNER + d]);   // z = cols [2048,4096)
    float y = h * Dv + xv;
    yg[row * DINNER + d] = f2bf(y * silu_f(zv));
  }
}

// ---------------- launch --------------------------------------------------------
extern "C" void kernel_launch(void* const* d_in, const int* in_sizes, int n_in,
                              void* d_out, int out_size, void* d_ws, size_t ws_size,
                              hipStream_t stream) {
  const float* x   = (const float*)d_in[0];
  const float* w1  = (const float*)d_in[1];
  const float* cw  = (const float*)d_in[2];
  const float* cb  = (const float*)d_in[3];
  const float* xpw = (const float*)d_in[4];
  const float* dtw = (const float*)d_in[5];
  const float* dtb = (const float*)d_in[6];
  const float* Dp  = (const float*)d_in[7];
  const float* w3  = (const float*)d_in[8];
  float* out = (float*)d_out;
  char* ws = (char*)d_ws;

  u16*   xb    = (u16*)(ws + 0);            // 16.78 MB
  u16*   w1b   = (u16*)(ws + 16777216);     //  8.39 MB
  u16*   w3b   = (u16*)(ws + 25165824);     //  4.19 MB
  u16*   xz    = (u16*)(ws + 29360128);     // 67.11 MB  [8192][4096] bf16
  u16*   xc    = (u16*)(ws + 96468992);     // 33.55 MB  [8192][2048] bf16
  u16*   yg    = (u16*)(ws + 130023424);    // 33.55 MB  [8192][2048] bf16
  float* bssm  = (float*)(ws + 163577856);  // 0.52 MB   [8192][16]
  float* alpha = (float*)(ws + 164102144);  // 32 KB     [8192]
  float* carry = (float*)(ws + 164135168);  // 0.52 MB   [64][2048] (doubles as Hs)
  u16*   xpwb  = (u16*)(ws + 164659456);    // 64 KB     [16][2048] bf16

  k_convert<<<14368, 256, 0, stream>>>(x, w1, w3, xpw, xb, w1b, w3b, xpwb);
  k_gemm_bt<4096, 1024, true ><<<dim3(32, 64), 256, 0, stream>>>(xb, w1b, xz);
  k_conv   <<<8192, 256, 0, stream>>>(xz, cw, cb, xc);
  k_bssm   <<<256, 256, 0, stream>>>(xc, xpwb, bssm);
  k_alpha  <<<512, 256, 0, stream>>>(bssm, dtw, dtb, alpha);
  k_scan1  <<<512, 256, 0, stream>>>(xc, alpha, carry);
  k_scan2  <<<32, 256, 0, stream>>>(carry, alpha);
  k_scan3  <<<512, 256, 0, stream>>>(xc, xz, alpha, carry, Dp, yg);
  k_gemm_bt<1024, 2048, false><<<dim3(8, 64), 256, 0, stream>>>(yg, w3b, out);
}